// Round 6
// baseline (911.197 us; speedup 1.0000x reference)
//
#include <hip/hip_runtime.h>
#include <hip/hip_bf16.h>
#include <math.h>

#define GH 721
#define GW 1440
#define C_IN 78
#define NNODES 5882
#define KNEIGH 128
#define M_TOTAL (NNODES * KNEIGH)   // 752896
#define TM 64
#define NBLOCKS (M_TOTAL / (2 * TM))   // 5882: two 64-row tiles per block

typedef __attribute__((ext_vector_type(8))) short bf16x8;
typedef __attribute__((ext_vector_type(4))) float f32x4;

__device__ __forceinline__ unsigned short f2bf(float x) {
    __hip_bfloat16 b = __float2bfloat16(x);
    union { __hip_bfloat16 h; unsigned short u; } cv; cv.h = b; return cv.u;
}

// ---------------- prep kernel (unchanged) ----------------
__global__ void prep_kernel(const float* __restrict__ W1, const float* __restrict__ W2,
                            const float* __restrict__ means, const float* __restrict__ stds,
                            const float* __restrict__ b1,
                            unsigned short* __restrict__ bp1, unsigned short* __restrict__ bp2,
                            float* __restrict__ latT, float* __restrict__ lonT,
                            float* __restrict__ b1p)
{
    const int NB1 = 3 * 4 * 256 * 8;   // 24576
    const int NB2 = 8 * 4 * 256 * 8;   // 65536
    const int NTOT = NB1 + NB2 + GH + GW + 256;
    for (int e = blockIdx.x * blockDim.x + threadIdx.x; e < NTOT;
         e += gridDim.x * blockDim.x) {
        if (e < NB1) {
            int j = e & 7, c = (e >> 3) & 255, o = (e >> 11) & 3, s = e >> 13;
            int k = s * 32 + o * 8 + j;
            float v = 0.f;
            if (k < 82) v = W1[k * 256 + c] / (stds[k] + 1e-7f);
            bp1[e] = f2bf(v);
        } else if (e < NB1 + NB2) {
            int t = e - NB1;
            int j = t & 7, c = (t >> 3) & 255, o = (t >> 11) & 3, s = t >> 13;
            int k = s * 32 + o * 8 + j;
            bp2[t] = f2bf(W2[k * 256 + c]);
        } else if (e < NB1 + NB2 + GH) {
            int h = e - NB1 - NB2;
            float r = (-90.f + 0.25f * (float)h) * 0.017453292519943295f;
            latT[2 * h]     = sinf(r);
            latT[2 * h + 1] = cosf(r);
        } else if (e < NB1 + NB2 + GH + GW) {
            int w = e - NB1 - NB2 - GH;
            float r = ((float)w * (360.f / 1439.f)) * 0.017453292519943295f;
            lonT[2 * w]     = sinf(r);
            lonT[2 * w + 1] = cosf(r);
        } else {
            int c = e - NB1 - NB2 - GH - GW;
            float acc = b1[c];
            #pragma unroll 1
            for (int k = 0; k < 86; ++k) {
                float inv = 1.f / (stds[k] + 1e-7f);
                float w = W1[k * 256 + c] * inv;
                acc -= means[k] * w;
                if (k == 82) acc += 0.5f * w;   // day-of-year channel, raw value 0.5
            }
            b1p[c] = acc;
        }
    }
}

// ---- per-tile compute: GEMM1 -> ReLU+LN -> GEMM2 -> staged full-line stores ----
__device__ __forceinline__ void compute_tile(
    char* smem, float (*red)[4][TM],
    const unsigned short* __restrict__ bp1, const unsigned short* __restrict__ bp2,
    const float* b1v, const float* lsv, const float* lov, const float* b2v,
    float* __restrict__ out, long gbase,
    int lane, int wave, int l15, int lg, int wbase)
{
    unsigned short* h_lds = (unsigned short*)smem;
    unsigned short (*x_lds)[104] = (unsigned short (*)[104])smem;
    float* otile = (float*)smem;

    // ---- GEMM1: x[64x96] @ W1'[96x256] ----
    f32x4 acc[4][4];
    #pragma unroll
    for (int mf = 0; mf < 4; ++mf)
        #pragma unroll
        for (int nf = 0; nf < 4; ++nf) acc[mf][nf] = (f32x4){0.f, 0.f, 0.f, 0.f};

    #pragma unroll
    for (int s = 0; s < 3; ++s) {
        bf16x8 af[4], bw[4];
        #pragma unroll
        for (int mf = 0; mf < 4; ++mf)
            af[mf] = *(const bf16x8*)&x_lds[mf * 16 + l15][s * 32 + lg * 8];
        #pragma unroll
        for (int nf = 0; nf < 4; ++nf)
            bw[nf] = *(const bf16x8*)(bp1 + ((size_t)((s * 4 + lg) * 256) + wbase + nf * 16 + l15) * 8);
        #pragma unroll
        for (int mf = 0; mf < 4; ++mf)
            #pragma unroll
            for (int nf = 0; nf < 4; ++nf)
                acc[mf][nf] = __builtin_amdgcn_mfma_f32_16x16x32_bf16(af[mf], bw[nf], acc[mf][nf], 0, 0, 0);
    }

    // ---- bias + ReLU + LN partials ----
    float sm[4][4], sq[4][4];
    #pragma unroll
    for (int mf = 0; mf < 4; ++mf)
        #pragma unroll
        for (int i = 0; i < 4; ++i) { sm[mf][i] = 0.f; sq[mf][i] = 0.f; }

    #pragma unroll
    for (int mf = 0; mf < 4; ++mf)
        #pragma unroll
        for (int nf = 0; nf < 4; ++nf)
            #pragma unroll
            for (int i = 0; i < 4; ++i) {
                float v = fmaxf(acc[mf][nf][i] + b1v[nf], 0.f);
                acc[mf][nf][i] = v;
                sm[mf][i] += v;
                sq[mf][i] += v * v;
            }

    #pragma unroll
    for (int m = 1; m < 16; m <<= 1)
        #pragma unroll
        for (int mf = 0; mf < 4; ++mf)
            #pragma unroll
            for (int i = 0; i < 4; ++i) {
                sm[mf][i] += __shfl_xor(sm[mf][i], m, 64);
                sq[mf][i] += __shfl_xor(sq[mf][i], m, 64);
            }

    if (l15 == 0) {
        #pragma unroll
        for (int mf = 0; mf < 4; ++mf)
            #pragma unroll
            for (int i = 0; i < 4; ++i) {
                int row = mf * 16 + lg * 4 + i;
                red[0][wave][row] = sm[mf][i];
                red[1][wave][row] = sq[mf][i];
            }
    }
    __syncthreads();

    // ---- LN finish -> bf16 h_lds (swizzled) ----
    #pragma unroll
    for (int mf = 0; mf < 4; ++mf)
        #pragma unroll
        for (int i = 0; i < 4; ++i) {
            int row = mf * 16 + lg * 4 + i;
            float tot = red[0][0][row] + red[0][1][row] + red[0][2][row] + red[0][3][row];
            float tq  = red[1][0][row] + red[1][1][row] + red[1][2][row] + red[1][3][row];
            float mean = tot * (1.f / 256.f);
            float var  = tq * (1.f / 256.f) - mean * mean;
            float rs = rsqrtf(var + 1e-5f);
            #pragma unroll
            for (int nf = 0; nf < 4; ++nf) {
                float v = (acc[mf][nf][i] - mean) * rs * lsv[nf] + lov[nf];
                int col = wbase + nf * 16 + l15;
                unsigned off = (unsigned)(row * 512 + col * 2);
                off ^= (unsigned)((row & 7) << 4);
                *(unsigned short*)((char*)h_lds + off) = f2bf(v);
            }
        }
    __syncthreads();

    // ---- GEMM2: h[64x256] @ W2[256x256] ----
    #pragma unroll
    for (int mf = 0; mf < 4; ++mf)
        #pragma unroll
        for (int nf = 0; nf < 4; ++nf) acc[mf][nf] = (f32x4){0.f, 0.f, 0.f, 0.f};

    #pragma unroll
    for (int s = 0; s < 8; ++s) {
        bf16x8 af[4], bw[4];
        #pragma unroll
        for (int mf = 0; mf < 4; ++mf) {
            int row = mf * 16 + l15;
            unsigned off = (unsigned)(row * 512 + (s * 32 + lg * 8) * 2);
            off ^= (unsigned)((row & 7) << 4);
            af[mf] = *(const bf16x8*)((char*)h_lds + off);
        }
        #pragma unroll
        for (int nf = 0; nf < 4; ++nf)
            bw[nf] = *(const bf16x8*)(bp2 + ((size_t)((s * 4 + lg) * 256) + wbase + nf * 16 + l15) * 8);
        #pragma unroll
        for (int mf = 0; mf < 4; ++mf)
            #pragma unroll
            for (int nf = 0; nf < 4; ++nf)
                acc[mf][nf] = __builtin_amdgcn_mfma_f32_16x16x32_bf16(af[mf], bw[nf], acc[mf][nf], 0, 0, 0);
    }

    // ---- epilogue: stage 32 rows in LDS (rotated), plain full-line stores ----
    // Rotation ((col + rl*4) & 255) keeps otile writes ~2-way (free); reads are
    // 64-lane contiguous 1 KB rows -> every store covers 8 full 128-B lines and
    // stays cacheable so L2 write-combines (nt forfeited that: 2x WRITE in R3-R5).
    #pragma unroll
    for (int p = 0; p < 2; ++p) {
        __syncthreads();   // p=0: GEMM2 LDS reads done; p=1: prev phase reads done
        #pragma unroll
        for (int mfl = 0; mfl < 2; ++mfl) {
            const int mf = p * 2 + mfl;
            #pragma unroll
            for (int i = 0; i < 4; ++i) {
                int rl = mfl * 16 + lg * 4 + i;     // 0..31
                #pragma unroll
                for (int nf = 0; nf < 4; ++nf) {
                    int col = wbase + nf * 16 + l15;
                    otile[rl * 256 + ((col + rl * 4) & 255)] = acc[mf][nf][i] + b2v[nf];
                }
            }
        }
        __syncthreads();
        #pragma unroll
        for (int r8 = 0; r8 < 8; ++r8) {
            const int rl = wave * 8 + r8;           // 0..31
            const long row_g = gbase + p * 32 + rl;
            f32x4 v = *(const f32x4*)&otile[rl * 256 + ((lane * 4 + rl * 4) & 255)];
            *(f32x4*)(out + row_g * 256 + lane * 4) = v;
        }
    }
}

// ---------------- fused kernel: 2 x 64-row tiles per block ----------------
__global__ __launch_bounds__(256, 4)
void fused_kernel(const float* __restrict__ var_grid, const int* __restrict__ idxs,
                  const unsigned short* __restrict__ bp1, const unsigned short* __restrict__ bp2,
                  const float* __restrict__ latT, const float* __restrict__ lonT,
                  const float* __restrict__ b1p, const float* __restrict__ lnS,
                  const float* __restrict__ lnO, const float* __restrict__ b2,
                  float* __restrict__ out)
{
    __shared__ __align__(16) char smem[TM * 256 * 2];   // 32 KiB: x | h | otile aliases
    __shared__ float red[2][4][TM];                     // 2 KiB LN partials

    unsigned short (*x_lds)[104] = (unsigned short (*)[104])smem;

    const int tid  = threadIdx.x;
    const int lane = tid & 63;
    const int wave = tid >> 6;       // 0..3
    const int l15  = lane & 15;
    const int lg   = lane >> 4;      // 0..3
    const int wbase = wave * 64;
    const long block0 = (long)blockIdx.x * (2 * TM);

    const int row = tid >> 2, p = tid & 3;       // 4 lanes per row

    // idx for both tiles up front (latency overlapped)
    const int idx0 = idxs[block0 + row];
    const int idx1 = idxs[block0 + TM + row];

    // ---- tile-0 gather -> regs -> pack ----
    {
        const int hh = idx0 / GW;
        const int ww = idx0 - hh * GW;
        const float* src = var_grid + (long)idx0 * C_IN;
        float2 g[10], tl, tl2;
        #pragma unroll
        for (int t = 0; t < 10; ++t) {
            const int q = p + 4 * t;
            if (q < 39) g[t] = *(const float2*)(src + 2 * q);
        }
        tl.x  = latT[2 * hh]; tl.y  = latT[2 * hh + 1];
        tl2.x = lonT[2 * ww]; tl2.y = lonT[2 * ww + 1];
        unsigned int* xrow = (unsigned int*)&x_lds[row][0];
        #pragma unroll
        for (int t = 0; t < 12; ++t) {
            const int q = p + 4 * t;
            float v0, v1;
            if (q < 39)      { v0 = g[t].x; v1 = g[t].y; }
            else if (q == 39){ v0 = tl.x;  v1 = tl.y; }
            else if (q == 40){ v0 = tl2.x; v1 = tl2.y; }
            else             { v0 = 0.f; v1 = 0.f; }
            xrow[q] = ((unsigned int)f2bf(v1) << 16) | (unsigned int)f2bf(v0);
        }
    }

    float b1v[4], lsv[4], lov[4], b2v[4];
    #pragma unroll
    for (int nf = 0; nf < 4; ++nf) {
        int col = wbase + nf * 16 + l15;
        b1v[nf] = b1p[col]; lsv[nf] = lnS[col]; lov[nf] = lnO[col]; b2v[nf] = b2[col];
    }
    __syncthreads();

    // ---- issue tile-1 gather loads NOW: latency hides under tile-0 compute ----
    float2 g1[10], tl1, tl21;
    {
        const int hh = idx1 / GW;
        const int ww = idx1 - hh * GW;
        const float* src = var_grid + (long)idx1 * C_IN;
        #pragma unroll
        for (int t = 0; t < 10; ++t) {
            const int q = p + 4 * t;
            if (q < 39) g1[t] = *(const float2*)(src + 2 * q);
        }
        tl1.x  = latT[2 * hh]; tl1.y  = latT[2 * hh + 1];
        tl21.x = lonT[2 * ww]; tl21.y = lonT[2 * ww + 1];
    }

    compute_tile(smem, red, bp1, bp2, b1v, lsv, lov, b2v, out, block0,
                 lane, wave, l15, lg, wbase);

    __syncthreads();   // all otile reads done before x_lds overwrite

    // ---- pack tile 1 (loads already resident) ----
    {
        unsigned int* xrow = (unsigned int*)&x_lds[row][0];
        #pragma unroll
        for (int t = 0; t < 12; ++t) {
            const int q = p + 4 * t;
            float v0, v1;
            if (q < 39)      { v0 = g1[t].x; v1 = g1[t].y; }
            else if (q == 39){ v0 = tl1.x;  v1 = tl1.y; }
            else if (q == 40){ v0 = tl21.x; v1 = tl21.y; }
            else             { v0 = 0.f; v1 = 0.f; }
            xrow[q] = ((unsigned int)f2bf(v1) << 16) | (unsigned int)f2bf(v0);
        }
    }
    __syncthreads();

    compute_tile(smem, red, bp1, bp2, b1v, lsv, lov, b2v, out, block0 + TM,
                 lane, wave, l15, lg, wbase);
}

extern "C" void kernel_launch(void* const* d_in, const int* in_sizes, int n_in,
                              void* d_out, int out_size, void* d_ws, size_t ws_size,
                              hipStream_t stream) {
    const float* var_grid = (const float*)d_in[0];
    const int*   idxs     = (const int*)d_in[1];
    const float* means    = (const float*)d_in[2];
    const float* stds     = (const float*)d_in[3];
    const float* W1       = (const float*)d_in[4];
    const float* b1       = (const float*)d_in[5];
    const float* lnS      = (const float*)d_in[6];
    const float* lnO      = (const float*)d_in[7];
    const float* W2       = (const float*)d_in[8];
    const float* b2       = (const float*)d_in[9];
    float* out = (float*)d_out;

    char* ws = (char*)d_ws;
    unsigned short* bp1 = (unsigned short*)ws;               // 49152 B
    unsigned short* bp2 = (unsigned short*)(ws + 49152);     // 131072 B -> 180224
    float* latT = (float*)(ws + 180224);                     // 5768 B
    float* lonT = (float*)(ws + 186000);                     // 11520 B
    float* b1p  = (float*)(ws + 197520);                     // 1024 B  (end 198544)

    prep_kernel<<<362, 256, 0, stream>>>(W1, W2, means, stds, b1, bp1, bp2, latT, lonT, b1p);
    fused_kernel<<<NBLOCKS, 256, 0, stream>>>(var_grid, idxs, bp1, bp2, latT, lonT,
                                              b1p, lnS, lnO, b2, out);
}

// Round 7
// 459.746 us; speedup vs baseline: 1.9820x; 1.9820x over previous
//
#include <hip/hip_runtime.h>
#include <hip/hip_bf16.h>
#include <math.h>

#define GH 721
#define GW 1440
#define C_IN 78
#define NNODES 5882
#define KNEIGH 128
#define M_TOTAL (NNODES * KNEIGH)   // 752896
#define TM 128
#define NBLOCKS (M_TOTAL / TM)      // 5882

typedef __attribute__((ext_vector_type(8))) short bf16x8;
typedef __attribute__((ext_vector_type(4))) float f32x4;

__device__ __forceinline__ unsigned short f2bf(float x) {
    __hip_bfloat16 b = __float2bfloat16(x);
    union { __hip_bfloat16 h; unsigned short u; } cv; cv.h = b; return cv.u;
}

// ---------------- prep kernel (unchanged) ----------------
__global__ void prep_kernel(const float* __restrict__ W1, const float* __restrict__ W2,
                            const float* __restrict__ means, const float* __restrict__ stds,
                            const float* __restrict__ b1,
                            unsigned short* __restrict__ bp1, unsigned short* __restrict__ bp2,
                            float* __restrict__ latT, float* __restrict__ lonT,
                            float* __restrict__ b1p)
{
    const int NB1 = 3 * 4 * 256 * 8;   // 24576
    const int NB2 = 8 * 4 * 256 * 8;   // 65536
    const int NTOT = NB1 + NB2 + GH + GW + 256;
    for (int e = blockIdx.x * blockDim.x + threadIdx.x; e < NTOT;
         e += gridDim.x * blockDim.x) {
        if (e < NB1) {
            int j = e & 7, c = (e >> 3) & 255, o = (e >> 11) & 3, s = e >> 13;
            int k = s * 32 + o * 8 + j;
            float v = 0.f;
            if (k < 82) v = W1[k * 256 + c] / (stds[k] + 1e-7f);
            bp1[e] = f2bf(v);
        } else if (e < NB1 + NB2) {
            int t = e - NB1;
            int j = t & 7, c = (t >> 3) & 255, o = (t >> 11) & 3, s = t >> 13;
            int k = s * 32 + o * 8 + j;
            bp2[t] = f2bf(W2[k * 256 + c]);
        } else if (e < NB1 + NB2 + GH) {
            int h = e - NB1 - NB2;
            float r = (-90.f + 0.25f * (float)h) * 0.017453292519943295f;
            latT[2 * h]     = sinf(r);
            latT[2 * h + 1] = cosf(r);
        } else if (e < NB1 + NB2 + GH + GW) {
            int w = e - NB1 - NB2 - GH;
            float r = ((float)w * (360.f / 1439.f)) * 0.017453292519943295f;
            lonT[2 * w]     = sinf(r);
            lonT[2 * w + 1] = cosf(r);
        } else {
            int c = e - NB1 - NB2 - GH - GW;
            float acc = b1[c];
            #pragma unroll 1
            for (int k = 0; k < 86; ++k) {
                float inv = 1.f / (stds[k] + 1e-7f);
                float w = W1[k * 256 + c] * inv;
                acc -= means[k] * w;
                if (k == 82) acc += 0.5f * w;   // day-of-year channel, raw value 0.5
            }
            b1p[c] = acc;
        }
    }
}

// ---------------- fused kernel: 128-row tile, 8 waves, 2 blocks/CU ----------------
__global__ __launch_bounds__(512, 4)
void fused_kernel(const float* __restrict__ var_grid, const int* __restrict__ idxs,
                  const unsigned short* __restrict__ bp1, const unsigned short* __restrict__ bp2,
                  const float* __restrict__ latT, const float* __restrict__ lonT,
                  const float* __restrict__ b1p, const float* __restrict__ lnS,
                  const float* __restrict__ lnO, const float* __restrict__ b2,
                  float* __restrict__ out)
{
    __shared__ __align__(16) char smem[TM * 256 * 2];   // 64 KiB: x | h aliases
    __shared__ float red[2][4][TM];                     // 4 KiB LN partials
    unsigned short* h_lds = (unsigned short*)smem;                    // [128][256] bf16 swizzled
    unsigned short (*x_lds)[104] = (unsigned short (*)[104])smem;     // [128][104] bf16

    // Bijective XCD-aware swizzle (nwg=5882, q=735, r=2): co-resident blocks on
    // an XCD become ~consecutive nodes -> gather patches overlap within L2.
    const int q_ = 735, r_ = 2;
    const int xcd = blockIdx.x & 7;
    const int ii  = blockIdx.x >> 3;
    const int swz = (xcd < r_ ? xcd * (q_ + 1) : r_ * (q_ + 1) + (xcd - r_) * q_) + ii;

    const int tid  = threadIdx.x;
    const int lane = tid & 63;
    const int wave = tid >> 6;       // 0..7
    const int wr   = wave >> 2;      // 0..1  row half
    const int wc   = wave & 3;       // 0..3  col quarter
    const int l15  = lane & 15;
    const int lg   = lane >> 4;      // 0..3
    const int wbase = wc * 64;
    const int rbase = wr * 64;
    const long block0 = (long)swz * TM;

    // ---- gather: batch loads -> regs, then pack -> LDS ----
    {
        const int row = tid >> 2, p = tid & 3;     // 4 lanes per row, rows 0..127
        const int idx = idxs[block0 + row];
        const int hh = idx / GW;
        const int ww = idx - hh * GW;
        const float* src = var_grid + (long)idx * C_IN;
        float2 g[10], tl, tl2;
        #pragma unroll
        for (int t = 0; t < 10; ++t) {
            const int q = p + 4 * t;
            if (q < 39) g[t] = *(const float2*)(src + 2 * q);
        }
        tl.x  = latT[2 * hh]; tl.y  = latT[2 * hh + 1];
        tl2.x = lonT[2 * ww]; tl2.y = lonT[2 * ww + 1];
        unsigned int* xrow = (unsigned int*)&x_lds[row][0];
        #pragma unroll
        for (int t = 0; t < 12; ++t) {
            const int q = p + 4 * t;
            float v0, v1;
            if (q < 39)      { v0 = g[t].x; v1 = g[t].y; }
            else if (q == 39){ v0 = tl.x;  v1 = tl.y; }
            else if (q == 40){ v0 = tl2.x; v1 = tl2.y; }
            else             { v0 = 0.f; v1 = 0.f; }
            xrow[q] = ((unsigned int)f2bf(v1) << 16) | (unsigned int)f2bf(v0);
        }
    }

    float b1v[4], lsv[4], lov[4], b2v[4];
    #pragma unroll
    for (int nf = 0; nf < 4; ++nf) {
        int col = wbase + nf * 16 + l15;
        b1v[nf] = b1p[col]; lsv[nf] = lnS[col]; lov[nf] = lnO[col]; b2v[nf] = b2[col];
    }
    __syncthreads();

    // ---- GEMM1: x[128x96] @ W1'[96x256], B prefetched 1 step ahead ----
    f32x4 acc[4][4];
    #pragma unroll
    for (int mf = 0; mf < 4; ++mf)
        #pragma unroll
        for (int nf = 0; nf < 4; ++nf) acc[mf][nf] = (f32x4){0.f, 0.f, 0.f, 0.f};

    bf16x8 bw[4], bwn[4];
    #pragma unroll
    for (int nf = 0; nf < 4; ++nf)
        bw[nf] = *(const bf16x8*)(bp1 + ((size_t)(lg * 256) + wbase + nf * 16 + l15) * 8);

    #pragma unroll
    for (int s = 0; s < 3; ++s) {
        if (s < 2)
            #pragma unroll
            for (int nf = 0; nf < 4; ++nf)
                bwn[nf] = *(const bf16x8*)(bp1 + ((size_t)(((s + 1) * 4 + lg) * 256) + wbase + nf * 16 + l15) * 8);
        bf16x8 af[4];
        #pragma unroll
        for (int mf = 0; mf < 4; ++mf)
            af[mf] = *(const bf16x8*)&x_lds[rbase + mf * 16 + l15][s * 32 + lg * 8];
        #pragma unroll
        for (int mf = 0; mf < 4; ++mf)
            #pragma unroll
            for (int nf = 0; nf < 4; ++nf)
                acc[mf][nf] = __builtin_amdgcn_mfma_f32_16x16x32_bf16(af[mf], bw[nf], acc[mf][nf], 0, 0, 0);
        #pragma unroll
        for (int nf = 0; nf < 4; ++nf) bw[nf] = bwn[nf];
    }

    // ---- bias + ReLU + LN partials ----
    float sm[4][4], sq[4][4];
    #pragma unroll
    for (int mf = 0; mf < 4; ++mf)
        #pragma unroll
        for (int i = 0; i < 4; ++i) { sm[mf][i] = 0.f; sq[mf][i] = 0.f; }

    #pragma unroll
    for (int mf = 0; mf < 4; ++mf)
        #pragma unroll
        for (int nf = 0; nf < 4; ++nf)
            #pragma unroll
            for (int i = 0; i < 4; ++i) {
                float v = fmaxf(acc[mf][nf][i] + b1v[nf], 0.f);
                acc[mf][nf][i] = v;
                sm[mf][i] += v;
                sq[mf][i] += v * v;
            }

    #pragma unroll
    for (int m = 1; m < 16; m <<= 1)
        #pragma unroll
        for (int mf = 0; mf < 4; ++mf)
            #pragma unroll
            for (int i = 0; i < 4; ++i) {
                sm[mf][i] += __shfl_xor(sm[mf][i], m, 64);
                sq[mf][i] += __shfl_xor(sq[mf][i], m, 64);
            }

    if (l15 == 0) {
        #pragma unroll
        for (int mf = 0; mf < 4; ++mf)
            #pragma unroll
            for (int i = 0; i < 4; ++i) {
                int row = rbase + mf * 16 + lg * 4 + i;
                red[0][wc][row] = sm[mf][i];
                red[1][wc][row] = sq[mf][i];
            }
    }
    __syncthreads();

    // ---- LN finish -> bf16 h_lds (swizzled) ----
    #pragma unroll
    for (int mf = 0; mf < 4; ++mf)
        #pragma unroll
        for (int i = 0; i < 4; ++i) {
            int row = rbase + mf * 16 + lg * 4 + i;
            float tot = red[0][0][row] + red[0][1][row] + red[0][2][row] + red[0][3][row];
            float tq  = red[1][0][row] + red[1][1][row] + red[1][2][row] + red[1][3][row];
            float mean = tot * (1.f / 256.f);
            float var  = tq * (1.f / 256.f) - mean * mean;
            float rs = rsqrtf(var + 1e-5f);
            #pragma unroll
            for (int nf = 0; nf < 4; ++nf) {
                float v = (acc[mf][nf][i] - mean) * rs * lsv[nf] + lov[nf];
                int col = wbase + nf * 16 + l15;
                unsigned off = (unsigned)(row * 512 + col * 2);
                off ^= (unsigned)((row & 7) << 4);
                *(unsigned short*)((char*)h_lds + off) = f2bf(v);
            }
        }
    __syncthreads();

    // ---- GEMM2: h[128x256] @ W2[256x256], B prefetched 1 step ahead ----
    #pragma unroll
    for (int mf = 0; mf < 4; ++mf)
        #pragma unroll
        for (int nf = 0; nf < 4; ++nf) acc[mf][nf] = (f32x4){0.f, 0.f, 0.f, 0.f};

    #pragma unroll
    for (int nf = 0; nf < 4; ++nf)
        bw[nf] = *(const bf16x8*)(bp2 + ((size_t)(lg * 256) + wbase + nf * 16 + l15) * 8);

    #pragma unroll
    for (int s = 0; s < 8; ++s) {
        if (s < 7)
            #pragma unroll
            for (int nf = 0; nf < 4; ++nf)
                bwn[nf] = *(const bf16x8*)(bp2 + ((size_t)(((s + 1) * 4 + lg) * 256) + wbase + nf * 16 + l15) * 8);
        bf16x8 af[4];
        #pragma unroll
        for (int mf = 0; mf < 4; ++mf) {
            int row = rbase + mf * 16 + l15;
            unsigned off = (unsigned)(row * 512 + (s * 32 + lg * 8) * 2);
            off ^= (unsigned)((row & 7) << 4);
            af[mf] = *(const bf16x8*)((char*)h_lds + off);
        }
        #pragma unroll
        for (int mf = 0; mf < 4; ++mf)
            #pragma unroll
            for (int nf = 0; nf < 4; ++nf)
                acc[mf][nf] = __builtin_amdgcn_mfma_f32_16x16x32_bf16(af[mf], bw[nf], acc[mf][nf], 0, 0, 0);
        #pragma unroll
        for (int nf = 0; nf < 4; ++nf) bw[nf] = bwn[nf];
    }

    // ---- epilogue: direct plain stores (64-B per quarter-wave; merges in L2
    //      at 2 blocks/CU per R1 evidence; nt and 4 blk/CU both broke this) ----
    #pragma unroll
    for (int mf = 0; mf < 4; ++mf)
        #pragma unroll
        for (int i = 0; i < 4; ++i) {
            long row_g = block0 + rbase + mf * 16 + lg * 4 + i;
            float* po = out + row_g * 256 + wbase;
            #pragma unroll
            for (int nf = 0; nf < 4; ++nf)
                po[nf * 16 + l15] = acc[mf][nf][i] + b2v[nf];
        }
}

extern "C" void kernel_launch(void* const* d_in, const int* in_sizes, int n_in,
                              void* d_out, int out_size, void* d_ws, size_t ws_size,
                              hipStream_t stream) {
    const float* var_grid = (const float*)d_in[0];
    const int*   idxs     = (const int*)d_in[1];
    const float* means    = (const float*)d_in[2];
    const float* stds     = (const float*)d_in[3];
    const float* W1       = (const float*)d_in[4];
    const float* b1       = (const float*)d_in[5];
    const float* lnS      = (const float*)d_in[6];
    const float* lnO      = (const float*)d_in[7];
    const float* W2       = (const float*)d_in[8];
    const float* b2       = (const float*)d_in[9];
    float* out = (float*)d_out;

    char* ws = (char*)d_ws;
    unsigned short* bp1 = (unsigned short*)ws;               // 49152 B
    unsigned short* bp2 = (unsigned short*)(ws + 49152);     // 131072 B -> 180224
    float* latT = (float*)(ws + 180224);                     // 5768 B
    float* lonT = (float*)(ws + 186000);                     // 11520 B
    float* b1p  = (float*)(ws + 197520);                     // 1024 B  (end 198544)

    prep_kernel<<<362, 256, 0, stream>>>(W1, W2, means, stds, b1, bp1, bp2, latT, lonT, b1p);
    fused_kernel<<<NBLOCKS, 512, 0, stream>>>(var_grid, idxs, bp1, bp2, latT, lonT,
                                              b1p, lnS, lnO, b2, out);
}